// Round 5
// baseline (387.293 us; speedup 1.0000x reference)
//
#include <hip/hip_runtime.h>

typedef _Float16 f16;
typedef _Float16 f16x2 __attribute__((ext_vector_type(2)));
typedef _Float16 f16x4 __attribute__((ext_vector_type(4)));
typedef _Float16 f16x8 __attribute__((ext_vector_type(8)));
typedef float f32x4 __attribute__((ext_vector_type(4)));

#define CIN 28
#define TT 8
#define HW 16384

// gate pre-scales folded into weights: i,f,o rows scaled by -log2e so
// E=exp2(acc)=e^{-x} and sig(x)=1/(1+E); g rows scaled by +2log2e so
// E=exp2(acc)=e^{2x} and tanh(x)=(E-1)/(E+1).
#define S_SIG  (-1.44269504088896341f)
#define S_TANH ( 2.88539008177792681f)

// workspace layout (bytes). Weight matrices stored in PACKED gate-row order:
//   pr = wave*32 + rt*16 + colpos*4 + gate,  col = 8*wave + 2*colpos + rt
// so a wave's 32 rows are 2 contiguous 16-row MFMA tiles, and within a tile
// thread quad qd holds rows 4qd..4qd+3 = all 4 gates of ONE hidden col.
#define WS_WX    0        // f16 [256][32]  folded Wih1*W_red (+denorm, gate scale)
#define WS_WHH1  16384    // f16 [256][64]
#define WS_W21   49152    // f16 [256][64]  folded Wih2*Wc1
#define WS_WHH2  81920    // f16 [256][64]
#define WS_BX    114688   // f32 [256]  packed order
#define WS_B2    115712   // f32 [256]  packed order
#define WS_WH    116736   // f32 [64]   folded W_head*Wc2 (ORIGINAL col order)
#define WS_BH    116992   // f32 [1]

// Fused LSTM cell activation: 5 exp2 + 2 rcp (sig(f) shares the i/g rcp:
// r3 = 1/((1+Ei)(1+Eg)(1+Ef)); cn = r3*(pig*c + (Eg-1)*pf) = c/pf + (Eg-1)/pig).
__device__ __forceinline__ float lstm_act(float gi, float gf, float gg, float go,
                                          float& c) {
  const float Ei = __builtin_amdgcn_exp2f(gi);
  const float Ef = __builtin_amdgcn_exp2f(gf);
  const float Eg = __builtin_amdgcn_exp2f(gg);
  const float Eo = __builtin_amdgcn_exp2f(go);
  const float pig = (1.f + Ei) * (1.f + Eg);
  const float pf  = 1.f + Ef;
  const float r3  = __builtin_amdgcn_rcpf(pig * pf);
  const float t1  = (Eg - 1.f) * pf;
  const float cn  = r3 * __builtin_fmaf(pig, c, t1);
  c = cn;
  const float Ec  = __builtin_amdgcn_exp2f(cn * S_TANH);
  const float roc = __builtin_amdgcn_rcpf((1.f + Eo) * (1.f + Ec));
  return (Ec - 1.f) * roc;
}

// Parallel prep: 256 blocks (one per ORIGINAL gate row g) x 64 threads (k).
__global__ __launch_bounds__(64) void prep_kernel(
    const float* __restrict__ W_red, const float* __restrict__ b_red,
    const float* __restrict__ Wih1, const float* __restrict__ Whh1,
    const float* __restrict__ bih1, const float* __restrict__ bhh1,
    const float* __restrict__ Wc1,  const float* __restrict__ bc1,
    const float* __restrict__ Wih2, const float* __restrict__ Whh2,
    const float* __restrict__ bih2, const float* __restrict__ bhh2,
    const float* __restrict__ Wc2,  const float* __restrict__ bc2,
    const float* __restrict__ W_head, const float* __restrict__ b_head,
    unsigned char* __restrict__ ws)
{
  const int g = blockIdx.x;    // 0..255 ORIGINAL gate row: gate = g>>6, col = g&63
  const int k = threadIdx.x;   // 0..63
  f16* WxH   = (f16*)(ws + WS_WX);
  f16* Whh1H = (f16*)(ws + WS_WHH1);
  f16* W21H  = (f16*)(ws + WS_W21);
  f16* Whh2H = (f16*)(ws + WS_WHH2);
  float* BX  = (float*)(ws + WS_BX);
  float* B2  = (float*)(ws + WS_B2);
  float* WHp = (float*)(ws + WS_WH);
  float* BHp = (float*)(ws + WS_BH);

  const int gate = g >> 6;
  const int col  = g & 63;
  // packed destination row: col = 8*wv + 2*cpos + rt
  const int pr = (col >> 3) * 32 + (col & 1) * 16 + ((col >> 1) & 3) * 4 + gate;

  const float sc = (gate == 2) ? S_TANH : S_SIG;  // gate g uses tanh

  // Wx[g][k] = Wih1[g,:] @ W_red[:,k]  (k < CIN), + u/v denorm fold
  float wxv = 0.f;
  if (k < CIN) {
    float s = 0.f;
    for (int r = 0; r < 24; ++r) s += Wih1[g*24 + r] * W_red[r*28 + k];
    wxv = s;
  }
  const float wx11 = __shfl(wxv, 11, 64);   // pre-scale values for bias fold
  const float wx12 = __shfl(wxv, 12, 64);
  if (k == 11) wxv *= 0.15f;                // SD_U
  if (k == 12) wxv *= 0.12f;                // SD_V
  if (k < 32) WxH[pr*32 + k] = (f16)(wxv * sc);

  Whh1H[pr*64 + k] = (f16)(Whh1[g*64 + k] * sc);
  Whh2H[pr*64 + k] = (f16)(Whh2[g*64 + k] * sc);

  // W21[g][k] = Wih2[g,:] @ Wc1[:,k]   (k = ORIGINAL h1 col, unpermuted)
  {
    float s = 0.f;
    for (int m = 0; m < 64; ++m) s += Wih2[g*64 + m] * Wc1[m*64 + k];
    W21H[pr*64 + k] = (f16)(s * sc);
  }

  if (k == 0) {
    float bx = bih1[g] + bhh1[g];
    for (int r = 0; r < 24; ++r) bx += Wih1[g*24 + r] * b_red[r];
    bx += wx11 * 0.02f + wx12 * (-0.01f);   // MU_U, MU_V
    BX[pr] = bx * sc;
    float b2v = bih2[g] + bhh2[g];
    for (int m = 0; m < 64; ++m) b2v += Wih2[g*64 + m] * bc1[m];
    B2[pr] = b2v * sc;
  }
  if (g == 0) {
    float s = 0.f;
    for (int m = 0; m < 64; ++m) s += W_head[m] * Wc2[m*64 + k];
    WHp[k] = s;
    if (k == 0) {
      float s2 = b_head[0];
      for (int m = 0; m < 64; ++m) s2 += W_head[m] * bc2[m];
      BHp[0] = s2;
    }
  }
}

// 64 pixels/block, 8 waves (512 threads); wave w owns hidden cols 8w..8w+7
// (x all 4 gates) as 2 packed row-tiles (56 VGPR of weights, 4 waves/SIMD).
//
// Sync structure: ONE barrier per timestep. The x_{t+1} staging store is
// placed BEFORE the barrier, so the barrier chain alone orders every LDS
// dependency (verified pairwise):
//   h1: L1(t+1) writes buf[t&1]  vs L1(t) reads   -> both sides of mid(t)
//   h1: L2(t)   reads  buf[(t+1)&1] written by L1(t) pre-mid(t)
//   h2: L2(t)   writes buf[(t+1)&1] vs L2(t+1) reads -> mid(t+1)
//   xs: stage(t+1) pre-mid(t) vs L1(t+1) reads post-mid(t)
//   xs: stage(t+2) writes buf[t&1] post-mid(t+1)? no: pre-mid(t+1); L1(t)
//       reads buf[t&1] pre-mid(t) <= mid(t+1)  -> ordered
// x global loads are issued a FULL iteration ahead (t+2), giving ~2 phases
// of latency headroom instead of <1.
//
// Swapped-operand MFMA: A = weights (packed rows), B = activations. Per
// D-tile, thread (cl,qd) holds rows 4qd+r = the 4 GATES of hidden col
// (8wv+2qd+rt), pixel cl -> one lstm_act per tile, rt pair -> one packed
// ds_write_b32. Bias is a contiguous f32x4 used as the MFMA C operand.
// All MFMAs are __builtins (compiler owns every hazard).
__global__ __launch_bounds__(512, 4)
void convlstm_main(
    const float* __restrict__ x, const unsigned char* __restrict__ ws,
    float* __restrict__ out)
{
  __shared__ __align__(16) f16 xs[2][64 * 40];       // [pixel][ch], stride 40
  __shared__ __align__(16) f16 h1buf[2][64 * 72];    // [pixel][hid], stride 72
  __shared__ __align__(16) f16 h2buf[2][64 * 72];

  const int tid  = threadIdx.x;
  const int lane = tid & 63;
  const int wv   = tid >> 6;     // wave 0..7
  const int cl   = lane & 15;    // MFMA "lane&15" (pixel within tile / A row)
  const int qd   = lane >> 4;    // MFMA quad

  const f16* WxG   = (const f16*)(ws + WS_WX);
  const f16* Whh1G = (const f16*)(ws + WS_WHH1);
  const f16* W21G  = (const f16*)(ws + WS_W21);
  const f16* Whh2G = (const f16*)(ws + WS_WHH2);
  const float* BX  = (const float*)(ws + WS_BX);
  const float* B2  = (const float*)(ws + WS_B2);

  // ---- weight fragments (A layout: m=cl -> packed row, k=8qd+j) ----
  f16x8 wx[2];                      // k 0..31
  f16x8 whh1[2][2], w21[2][2], whh2[2][2];   // [rt][k-half]
  f32x4 bxq[2], b2q[2];             // rows 4qd..4qd+3 of each row-tile
#pragma unroll
  for (int rt = 0; rt < 2; ++rt) {
    const int pr = wv*32 + rt*16 + cl;
    wx[rt]      = *(const f16x8*)(WxG + pr*32 + qd*8);
    whh1[rt][0] = *(const f16x8*)(Whh1G + pr*64 + qd*8);
    whh1[rt][1] = *(const f16x8*)(Whh1G + pr*64 + 32 + qd*8);
    w21[rt][0]  = *(const f16x8*)(W21G  + pr*64 + qd*8);
    w21[rt][1]  = *(const f16x8*)(W21G  + pr*64 + 32 + qd*8);
    whh2[rt][0] = *(const f16x8*)(Whh2G + pr*64 + qd*8);
    whh2[rt][1] = *(const f16x8*)(Whh2G + pr*64 + 32 + qd*8);
    bxq[rt] = *(const f32x4*)(BX + wv*32 + rt*16 + 4*qd);
    b2q[rt] = *(const f32x4*)(B2 + wv*32 + rt*16 + 4*qd);
  }

  // zero t=0 h buffers (buffer 0 of each)
  {
    unsigned* z1 = (unsigned*)&h1buf[0][0];
    unsigned* z2 = (unsigned*)&h2buf[0][0];
#pragma unroll
    for (int i = tid; i < 2304; i += 512) { z1[i] = 0u; z2[i] = 0u; }
  }

  const int gpix = blockIdx.x * 64;
  const float* xb = x + (size_t)(gpix >> 14) * (TT * CIN * HW) + (gpix & (HW - 1));

  const int sp = lane;        // staging pixel (coalesced per wave)
  const int cg = wv;          // channel group: ch = 4cg..4cg+3

  // stage x_0 directly; load x_1 into the prefetch register
  {
    f16x4 v;
#pragma unroll
    for (int j = 0; j < 4; ++j) {
      const int ch = cg*4 + j;
      v[j] = (ch < CIN) ? (f16)xb[ch*HW + sp] : (f16)0.f;
    }
    *(f16x4*)(&xs[0][sp*40 + cg*4]) = v;
  }
  f16x4 xrv;   // holds x_{t+1} at the top of iteration t
  {
    const float* xt = xb + (size_t)(CIN * HW);
#pragma unroll
    for (int j = 0; j < 4; ++j) {
      const int ch = cg*4 + j;
      xrv[j] = (ch < CIN) ? (f16)xt[ch*HW + sp] : (f16)0.f;
    }
  }
  __syncthreads();

  float c1s[4][2];   // [mb][rt]
  float c2s[4][2];
#pragma unroll
  for (int a = 0; a < 4; ++a)
#pragma unroll
    for (int b = 0; b < 2; ++b) { c1s[a][b] = 0.f; c2s[a][b] = 0.f; }

#pragma unroll 1
  for (int t = 0; t < TT; ++t) {
    const f16* xsr = xs[t & 1];
    const f16* h1r = h1buf[t & 1];
    const f16* h2r = h2buf[t & 1];
    f16* h1w = h1buf[(t + 1) & 1];
    f16* h2w = h2buf[(t + 1) & 1];

    // ---- layer 1: gates = Whh1*h1 + Wx*x + bx (bias as C operand) ----
#pragma unroll
    for (int mb = 0; mb < 4; ++mb) {
      const int p = 16*mb + cl;
      const f16x8 ax  = *(const f16x8*)(xsr + p*40 + qd*8);
      const f16x8 ah0 = *(const f16x8*)(h1r + p*72 + qd*8);
      const f16x8 ah1 = *(const f16x8*)(h1r + p*72 + 32 + qd*8);
      float hn[2];
#pragma unroll
      for (int rt = 0; rt < 2; ++rt) {
        f32x4 acc;
        acc = __builtin_amdgcn_mfma_f32_16x16x32_f16(whh1[rt][0], ah0, bxq[rt], 0, 0, 0);
        acc = __builtin_amdgcn_mfma_f32_16x16x32_f16(whh1[rt][1], ah1, acc, 0, 0, 0);
        acc = __builtin_amdgcn_mfma_f32_16x16x32_f16(wx[rt],      ax,  acc, 0, 0, 0);
        hn[rt] = lstm_act(acc[0], acc[1], acc[2], acc[3], c1s[mb][rt]);
      }
      f16x2 hv; hv[0] = (f16)hn[0]; hv[1] = (f16)hn[1];
      *(f16x2*)(h1w + p*72 + 8*wv + 2*qd) = hv;    // one ds_write_b32
    }

    // ---- stage x_{t+1} (pre-barrier: the single mid barrier orders it
    //      against L1(t+1)'s reads), then issue loads for x_{t+2} ----
    if (t + 1 < TT) {
      *(f16x4*)(xs[(t + 1) & 1] + sp*40 + cg*4) = xrv;
    }
    if (t + 2 < TT) {
      const float* xt = xb + (size_t)(t + 2) * (CIN * HW);
#pragma unroll
      for (int j = 0; j < 4; ++j) {
        const int ch = cg*4 + j;
        xrv[j] = (ch < CIN) ? (f16)xt[ch*HW + sp] : (f16)0.f;
      }
    }

    __syncthreads();   // the ONLY barrier per timestep

    // ---- layer 2: gates = W21*h1_new + Whh2*h2 + b2 (bias as C operand) ----
#pragma unroll
    for (int mb = 0; mb < 4; ++mb) {
      const int p = 16*mb + cl;
      const f16x8 an0 = *(const f16x8*)(h1w + p*72 + qd*8);
      const f16x8 an1 = *(const f16x8*)(h1w + p*72 + 32 + qd*8);
      const f16x8 a20 = *(const f16x8*)(h2r + p*72 + qd*8);
      const f16x8 a21 = *(const f16x8*)(h2r + p*72 + 32 + qd*8);
      float hn[2];
#pragma unroll
      for (int rt = 0; rt < 2; ++rt) {
        f32x4 acc;
        acc = __builtin_amdgcn_mfma_f32_16x16x32_f16(w21[rt][0],  an0, b2q[rt], 0, 0, 0);
        acc = __builtin_amdgcn_mfma_f32_16x16x32_f16(w21[rt][1],  an1, acc, 0, 0, 0);
        acc = __builtin_amdgcn_mfma_f32_16x16x32_f16(whh2[rt][0], a20, acc, 0, 0, 0);
        acc = __builtin_amdgcn_mfma_f32_16x16x32_f16(whh2[rt][1], a21, acc, 0, 0, 0);
        hn[rt] = lstm_act(acc[0], acc[1], acc[2], acc[3], c2s[mb][rt]);
      }
      f16x2 hv; hv[0] = (f16)hn[0]; hv[1] = (f16)hn[1];
      *(f16x2*)(h2w + p*72 + 8*wv + 2*qd) = hv;
    }
    // no end-of-t barrier: L1(t+1) touches no buffer L2(t) reads (see header)
  }
  __syncthreads();     // h2buf[0] complete before the head reads it

  // ---- head epilogue: out[p] = bhead + sum_k h2[p][k] * wh[k] ----
  if (tid < 64) {
    const float* wh = (const float*)(ws + WS_WH);
    const f16* row = &h2buf[0][tid * 72];   // final h2 lives in buffer 0
    float s = *((const float*)(ws + WS_BH));
#pragma unroll
    for (int k = 0; k < 64; ++k) s += (float)row[k] * wh[k];
    out[gpix + tid] = s;
  }
}

extern "C" void kernel_launch(void* const* d_in, const int* in_sizes, int n_in,
                              void* d_out, int out_size, void* d_ws, size_t ws_size,
                              hipStream_t stream) {
  const float* x      = (const float*)d_in[0];
  const float* W_red  = (const float*)d_in[1];
  const float* b_red  = (const float*)d_in[2];
  const float* Wih1   = (const float*)d_in[3];
  const float* Whh1   = (const float*)d_in[4];
  const float* bih1   = (const float*)d_in[5];
  const float* bhh1   = (const float*)d_in[6];
  const float* Wc1    = (const float*)d_in[7];
  const float* bc1    = (const float*)d_in[8];
  const float* Wih2   = (const float*)d_in[9];
  const float* Whh2   = (const float*)d_in[10];
  const float* bih2   = (const float*)d_in[11];
  const float* bhh2   = (const float*)d_in[12];
  const float* Wc2    = (const float*)d_in[13];
  const float* bc2    = (const float*)d_in[14];
  const float* W_head = (const float*)d_in[15];
  const float* b_head = (const float*)d_in[16];

  prep_kernel<<<256, 64, 0, stream>>>(W_red, b_red, Wih1, Whh1, bih1, bhh1,
                                      Wc1, bc1, Wih2, Whh2, bih2, bhh2,
                                      Wc2, bc2, W_head, b_head,
                                      (unsigned char*)d_ws);
  convlstm_main<<<2048, 512, 0, stream>>>(x, (const unsigned char*)d_ws,
                                          (float*)d_out);
}